// Round 1
// 889.814 us; speedup vs baseline: 1.0471x; 1.0471x over previous
//
#include <hip/hip_runtime.h>
#include <float.h>

// Problem constants (B=32 queries, D=128, K=16).
#define BQ 32
#define DIM 128
#define TOPK 16
#define G1 512          // phase-1 blocks (exactly 2 per CU)
#define T1 256          // phase-1 threads (4 waves)
#define T2 256          // phase-2 threads
#define NCAND (G1*16)   // candidates per query entering phase 2 = 8192

typedef float f32x16 __attribute__((ext_vector_type(16)));
typedef __bf16 bf16x8 __attribute__((ext_vector_type(8)));
typedef unsigned int u32x4 __attribute__((ext_vector_type(4)));

// pack: low16 = bf16_rne(a), high16 = bf16_rne(b)
static __device__ __forceinline__ unsigned cvt_pk_bf16(float a, float b) {
    unsigned r;
    asm("v_cvt_pk_bf16_f32 %0, %1, %2" : "=v"(r) : "v"(a), "v"(b));
    return r;
}

// 3-level RNE bf16 split of a float pair. x = h + m + l + O(2^-27 |x|).
// Residuals are Sterbenz-exact fp32 subtractions.
static __device__ __forceinline__ void split3(float f0, float f1,
                                              unsigned &h01, unsigned &m01, unsigned &l01) {
    h01 = cvt_pk_bf16(f0, f1);
    float r0 = f0 - __uint_as_float(h01 << 16);
    float r1 = f1 - __uint_as_float(h01 & 0xffff0000u);
    m01 = cvt_pk_bf16(r0, r1);
    float s0 = r0 - __uint_as_float(m01 << 16);
    float s1 = r1 - __uint_as_float(m01 & 0xffff0000u);
    l01 = cvt_pk_bf16(s0, s1);
}

static __device__ __forceinline__ f32x16 mfma32(u32x4 a, u32x4 b, f32x16 c) {
    return __builtin_amdgcn_mfma_f32_32x32x16_bf16(
        __builtin_bit_cast(bf16x8, a), __builtin_bit_cast(bf16x8, b), c, 0, 0, 0);
}

// ---------------- phase 0: q = query @ Wq^T + bq (stored transposed) + norms ----------
__global__ void ph0_qproj(const float* __restrict__ query, const float* __restrict__ Wq,
                          const float* __restrict__ bq,
                          float* __restrict__ qT, float* __restrict__ qn2,
                          float* __restrict__ sinvq)
{
    const int b = blockIdx.x;     // query row
    const int d = threadIdx.x;    // output dim
    float s = bq[d];
    #pragma unroll 8
    for (int kk = 0; kk < DIM; ++kk)
        s = fmaf(query[b * DIM + kk], Wq[d * DIM + kk], s);
    qT[d * BQ + b] = s;
    __shared__ float red[DIM];
    red[d] = s * s;
    __syncthreads();
    for (int off = DIM / 2; off >= 1; off >>= 1) {
        if (d < off) red[d] += red[d + off];
        __syncthreads();
    }
    if (d == 0) {
        qn2[b] = red[0];
        sinvq[b] = 1.0f / sqrtf(red[0]);
    }
}

// ---------------- phase 1: MFMA scores + per-block top-16/query + min-d2 ----------
// Per wave: 32-row x 32-query tile via v_mfma_f32_32x32x16_bf16, fp32 emulated by
// 3-way bf16 split (6 passes).  C-layout: col(query)=lane&31,
// row=(reg&3)+8*(reg>>2)+4*(lane>>5)  [m74/m101-verified].
__global__ __launch_bounds__(T1, 2) void ph1_scan(
    const float* __restrict__ mem, const float* __restrict__ imp,
    const int* __restrict__ tsp, const float* __restrict__ qT,
    const float* __restrict__ sinvq, const float* __restrict__ qn2,
    const int* __restrict__ ctp,
    float* __restrict__ cand_sc, int* __restrict__ cand_ix,
    float* __restrict__ minD_ws, int N, int C)
{
    __shared__ float dsc[T1 * TOPK];          // 16 KB
    __shared__ int   dix[T1 * TOPK];          // 16 KB
    __shared__ float dmn[T1];                 // 1 KB
    __shared__ float4 cbuf[4][BQ];            // 2 KB: per-wave row constants

    const int tid  = threadIdx.x;
    const int wave = tid >> 6;
    const int lane = tid & 63;
    const int qsel = lane & 31;               // query for score phase; row for A/consts
    const int hsel = lane >> 5;
    const int g = blockIdx.x;
    const int n0 = g * C;
    const int n1 = (n0 + C < N) ? (n0 + C) : N;

    const float invct = 1.0f / ((float)(*ctp) + 1.0f);
    const float sq   = sinvq[qsel];
    const float qn2s = qn2[qsel];

    // ---- build q fragments once per block: B-operand layout ----
    // B[k][n]: lane l holds col=l&31, k = t*16 + (l>>5)*8 + j (j contiguous).
    u32x4 Bh[8], Bm[8], Bl[8];
    #pragma unroll
    for (int t = 0; t < 8; ++t) {
        float x[8];
        #pragma unroll
        for (int j = 0; j < 8; ++j)
            x[j] = qT[(t * 16 + hsel * 8 + j) * BQ + qsel];
        #pragma unroll
        for (int p = 0; p < 4; ++p) {
            unsigned h, m, l;
            split3(x[2 * p], x[2 * p + 1], h, m, l);
            Bh[t][p] = h; Bm[t][p] = m; Bl[t][p] = l;
        }
    }

    float top_s[TOPK]; int top_i[TOPK];
    #pragma unroll
    for (int j = 0; j < TOPK; ++j) { top_s[j] = -FLT_MAX; top_i[j] = 0; }
    float mind = FLT_MAX;

    const int rlast = n1 - 1;
    for (int rb = n0 + wave * 32; rb < n1; rb += 4 * 32) {
        // A row for this lane (clamped; invalid rows masked in score phase)
        const int arow = rb + qsel;
        const int arc  = (arow < rlast) ? arow : rlast;
        const float* rp = mem + (size_t)arc * DIM + hsel * 8;

        f32x16 acc = { 0.f, 0.f, 0.f, 0.f, 0.f, 0.f, 0.f, 0.f,
                       0.f, 0.f, 0.f, 0.f, 0.f, 0.f, 0.f, 0.f };
        float m2p = 0.0f;

        #pragma unroll
        for (int t = 0; t < 8; ++t) {
            const float4 xa = *(const float4*)(rp + t * 16);
            const float4 xb = *(const float4*)(rp + t * 16 + 4);
            const float xs[8] = { xa.x, xa.y, xa.z, xa.w, xb.x, xb.y, xb.z, xb.w };
            u32x4 Ah, Am, Al;
            #pragma unroll
            for (int p = 0; p < 4; ++p) {
                unsigned h, m, l;
                split3(xs[2 * p], xs[2 * p + 1], h, m, l);
                Ah[p] = h; Am[p] = m; Al[p] = l;
                m2p = fmaf(xs[2 * p], xs[2 * p], m2p);
                m2p = fmaf(xs[2 * p + 1], xs[2 * p + 1], m2p);
            }
            // accumulate small terms first
            acc = mfma32(Al, Bh[t], acc);
            acc = mfma32(Am, Bm[t], acc);
            acc = mfma32(Ah, Bl[t], acc);
            acc = mfma32(Am, Bh[t], acc);
            acc = mfma32(Ah, Bm[t], acc);
            acc = mfma32(Ah, Bh[t], acc);
        }

        // per-row constants (row = rb + qsel); halves hold complementary k-chunks
        const float m2full = m2p + __shfl_xor(m2p, 32);
        const int crow = rb + qsel;
        const int crc  = (crow < rlast) ? crow : rlast;
        const float impf = fmaf(0.5f, imp[crc], 0.5f);
        const float recn = ((float)tsp[crc] + 1.0f) * invct;
        const float invm = rsqrtf(m2full);
        cbuf[wave][qsel] = make_float4(0.7f * invm * impf,
                                       0.3f * recn * impf,
                                       m2full,
                                       (crow < n1) ? 1.0f : -1.0f);
        // wave-private LDS; same-wave ds ordering, no barrier needed
        #pragma unroll
        for (int reg = 0; reg < 16; ++reg) {
            const int r = (reg & 3) + 8 * (reg >> 2) + 4 * hsel;
            const float4 cc = cbuf[wave][r];
            const float dot = acc[reg];
            const float score = fmaf(dot, cc.x * sq, cc.y);
            const float d2 = fmaf(-2.0f, dot, qn2s + cc.z);
            if (cc.w > 0.0f) {
                mind = fminf(mind, d2);
                if (score > top_s[TOPK - 1]) {
                    float cs = score; int ci = rb + r;
                    #pragma unroll
                    for (int p = 0; p < TOPK; ++p) {
                        const bool gt = cs > top_s[p];
                        const float tv = top_s[p]; const int tx = top_i[p];
                        top_s[p] = gt ? cs : tv;  top_i[p] = gt ? ci : tx;
                        cs = gt ? tv : cs;        ci = gt ? tx : ci;
                    }
                }
            }
        }
    }

    // ---- block merge: dump lists to LDS, per-query 128 -> 16 extraction ----
    #pragma unroll
    for (int j = 0; j < TOPK; ++j) {
        dsc[tid * TOPK + j] = top_s[j];
        dix[tid * TOPK + j] = top_i[j];
    }
    dmn[tid] = mind;
    __syncthreads();

    for (int qq = 0; qq < 8; ++qq) {
        const int q = wave * 8 + qq;
        // 8 lists of 16 -> 128 candidates; 2 per lane
        float sc2[2]; int ix2[2];
        #pragma unroll
        for (int s = 0; s < 2; ++s) {
            const int c = lane * 2 + s;
            const int L = (c >> 4) * 32 + q;
            const int slot = c & 15;
            sc2[s] = dsc[L * TOPK + slot];
            ix2[s] = dix[L * TOPK + slot];
        }
        float lm = (sc2[0] >= sc2[1]) ? sc2[0] : sc2[1];
        int   ls = (sc2[0] >= sc2[1]) ? 0 : 1;
        for (int r = 0; r < TOPK; ++r) {
            float v = lm; int we = lane;
            #pragma unroll
            for (int off = 32; off >= 1; off >>= 1) {
                const float ov = __shfl_xor(v, off);
                const int   oe = __shfl_xor(we, off);
                if (ov > v || (ov == v && oe < we)) { v = ov; we = oe; }
            }
            if (lane == we) {
                cand_sc[(g * 32 + q) * TOPK + r] = lm;
                cand_ix[(g * 32 + q) * TOPK + r] = ix2[ls];
                sc2[ls] = -FLT_MAX;
                lm = (sc2[0] >= sc2[1]) ? sc2[0] : sc2[1];
                ls = (sc2[0] >= sc2[1]) ? 0 : 1;
            }
        }
    }

    if (tid < 32) {
        float m = FLT_MAX;
        #pragma unroll
        for (int l = 0; l < 8; ++l) m = fminf(m, dmn[l * 32 + tid]);
        minD_ws[g * 32 + tid] = m;
    }
}

// ---------------- phase 2: global top-16/query + novelty ----------
__global__ void ph2_final(const float* __restrict__ cand_sc, const int* __restrict__ cand_ix,
                          const float* __restrict__ minD_ws, float* __restrict__ out, int G)
{
    __shared__ float ssc[NCAND];          // 32 KB
    __shared__ float shv[4];
    __shared__ int   she[4];
    __shared__ float smin[T2];

    const int q = blockIdx.x;
    const int tid = threadIdx.x;
    const int wave = tid >> 6;
    const int lane = tid & 63;

    for (int e = tid; e < NCAND; e += T2)
        ssc[e] = cand_sc[(e >> 4) * (32 * TOPK) + q * TOPK + (e & 15)];
    __syncthreads();

    // local argmax over this thread's 32 slots (e = s*256 + tid)
    float lm = ssc[tid]; int le = tid;
    for (int s = 1; s < NCAND / T2; ++s) {
        const int e = s * T2 + tid;
        const float v = ssc[e];
        if (v > lm) { lm = v; le = e; }
    }

    for (int r = 0; r < TOPK; ++r) {
        float v = lm; int e = le;
        #pragma unroll
        for (int off = 32; off >= 1; off >>= 1) {
            const float ov = __shfl_xor(v, off);
            const int   oe = __shfl_xor(e, off);
            if (ov > v || (ov == v && oe < e)) { v = ov; e = oe; }
        }
        if (lane == 0) { shv[wave] = v; she[wave] = e; }
        __syncthreads();
        float bv = shv[0]; int be = she[0];
        #pragma unroll
        for (int w2 = 1; w2 < 4; ++w2) {
            const float wv = shv[w2]; const int we2 = she[w2];
            if (wv > bv || (wv == bv && we2 < be)) { bv = wv; be = we2; }
        }
        if (le == be) {   // unique winner thread
            out[q * TOPK + r] = bv;
            const int gix = cand_ix[(be >> 4) * (32 * TOPK) + q * TOPK + (be & 15)];
            out[BQ * TOPK + q * TOPK + r] = (float)gix;
            ssc[le] = -FLT_MAX;
            lm = ssc[tid]; le = tid;
            for (int s = 1; s < NCAND / T2; ++s) {
                const int e2 = s * T2 + tid;
                const float v2 = ssc[e2];
                if (v2 > lm) { lm = v2; le = e2; }
            }
        }
        __syncthreads();
    }

    // novelty
    float m = FLT_MAX;
    for (int g2 = tid; g2 < G; g2 += T2) m = fminf(m, minD_ws[g2 * 32 + q]);
    smin[tid] = m;
    __syncthreads();
    for (int off = T2 / 2; off >= 1; off >>= 1) {
        if (tid < off) smin[tid] = fminf(smin[tid], smin[tid + off]);
        __syncthreads();
    }
    if (tid == 0) {
        const float md = sqrtf(fmaxf(smin[0], 0.0f));
        out[2 * BQ * TOPK + q] = fminf(1.0f, md * 0.1f);
    }
}

extern "C" void kernel_launch(void* const* d_in, const int* in_sizes, int n_in,
                              void* d_out, int out_size, void* d_ws, size_t ws_size,
                              hipStream_t stream) {
    const float* query      = (const float*)d_in[0];
    const float* memory     = (const float*)d_in[1];
    const float* importance = (const float*)d_in[2];
    const int*   timestamps = (const int*)d_in[3];
    const float* Wq         = (const float*)d_in[4];
    const float* bq         = (const float*)d_in[5];
    const int*   ctp        = (const int*)d_in[6];
    const int N = in_sizes[2];

    float* ws      = (float*)d_ws;
    float* qT      = ws;                       // 4096
    float* qn2     = ws + 4096;                // 32
    float* sinvq   = ws + 4128;                // 32
    float* cand_sc = ws + 4352;                // G1*32*16 = 262144
    int*   cand_ix = (int*)(ws + 4352 + G1 * 32 * TOPK);
    float* minD_ws = ws + 4352 + 2 * G1 * 32 * TOPK;  // G1*32

    const int C = (N + G1 - 1) / G1;           // rows per block

    ph0_qproj<<<BQ, DIM, 0, stream>>>(query, Wq, bq, qT, qn2, sinvq);
    ph1_scan<<<G1, T1, 0, stream>>>(memory, importance, timestamps, qT, sinvq, qn2,
                                    ctp, cand_sc, cand_ix, minD_ws, N, C);
    ph2_final<<<BQ, T2, 0, stream>>>(cand_sc, cand_ix, minD_ws, (float*)d_out, G1);
}

// Round 2
// 866.875 us; speedup vs baseline: 1.0748x; 1.0265x over previous
//
#include <hip/hip_runtime.h>
#include <float.h>

// Problem constants (B=32 queries, D=128, K=16).
#define BQ 32
#define DIM 128
#define TOPK 16
#define G1 768          // phase-1 blocks (3 per CU, balanced)
#define T1 256          // phase-1 threads (4 waves)
#define T2 256          // phase-2 threads
#define NCAND (G1*16)   // candidates per query entering phase 2 = 12288

typedef float f32x16 __attribute__((ext_vector_type(16)));
typedef __bf16 bf16x8 __attribute__((ext_vector_type(8)));
typedef unsigned int u32x4 __attribute__((ext_vector_type(4)));

// pack: low16 = bf16_rne(a), high16 = bf16_rne(b)
static __device__ __forceinline__ unsigned cvt_pk_bf16(float a, float b) {
    unsigned r;
    asm("v_cvt_pk_bf16_f32 %0, %1, %2" : "=v"(r) : "v"(a), "v"(b));
    return r;
}

// 3-level RNE bf16 split of a float pair. x = h + m + l + O(2^-27 |x|).
static __device__ __forceinline__ void split3(float f0, float f1,
                                              unsigned &h01, unsigned &m01, unsigned &l01) {
    h01 = cvt_pk_bf16(f0, f1);
    float r0 = f0 - __uint_as_float(h01 << 16);
    float r1 = f1 - __uint_as_float(h01 & 0xffff0000u);
    m01 = cvt_pk_bf16(r0, r1);
    float s0 = r0 - __uint_as_float(m01 << 16);
    float s1 = r1 - __uint_as_float(m01 & 0xffff0000u);
    l01 = cvt_pk_bf16(s0, s1);
}

static __device__ __forceinline__ f32x16 mfma32(u32x4 a, u32x4 b, f32x16 c) {
    return __builtin_amdgcn_mfma_f32_32x32x16_bf16(
        __builtin_bit_cast(bf16x8, a), __builtin_bit_cast(bf16x8, b), c, 0, 0, 0);
}

// ---------------- phase 0: q = query @ Wq^T + bq (stored transposed) + norms ----------
__global__ void ph0_qproj(const float* __restrict__ query, const float* __restrict__ Wq,
                          const float* __restrict__ bq,
                          float* __restrict__ qT, float* __restrict__ qn2,
                          float* __restrict__ sinvq)
{
    const int b = blockIdx.x;     // query row
    const int d = threadIdx.x;    // output dim
    float s = bq[d];
    #pragma unroll 8
    for (int kk = 0; kk < DIM; ++kk)
        s = fmaf(query[b * DIM + kk], Wq[d * DIM + kk], s);
    qT[d * BQ + b] = s;
    __shared__ float red[DIM];
    red[d] = s * s;
    __syncthreads();
    for (int off = DIM / 2; off >= 1; off >>= 1) {
        if (d < off) red[d] += red[d + off];
        __syncthreads();
    }
    if (d == 0) {
        qn2[b] = red[0];
        sinvq[b] = 1.0f / sqrtf(red[0]);
    }
}

// ---------------- phase 1: MFMA scores + per-block top-16/query + min-d2 ----------
// Per wave: 32-row x 32-query tile via v_mfma_f32_32x32x16_bf16, fp32 emulated by
// 3-way bf16 split (6 passes).  C-layout: col(query)=lane&31,
// row=(reg&3)+8*(reg>>2)+4*(lane>>5)  [m74/m101-verified].
__global__ __launch_bounds__(T1, 3) void ph1_scan(
    const float* __restrict__ mem, const float* __restrict__ imp,
    const int* __restrict__ tsp, const float* __restrict__ qT,
    const float* __restrict__ sinvq, const float* __restrict__ qn2,
    const int* __restrict__ ctp,
    float* __restrict__ cand_sc, int* __restrict__ cand_ix,
    float* __restrict__ minD_ws, int N, int C)
{
    __shared__ float dsc[T1 * TOPK];          // 16 KB
    __shared__ int   dix[T1 * TOPK];          // 16 KB
    __shared__ float dmn[T1];                 // 1 KB
    __shared__ float4 cbuf[4][BQ];            // 2 KB: per-wave row constants
    __shared__ float thr_s[BQ];               // block-shared per-query score bound

    const int tid  = threadIdx.x;
    const int wave = tid >> 6;
    const int lane = tid & 63;
    const int qsel = lane & 31;               // query for score phase; row for A/consts
    const int hsel = lane >> 5;
    const int g = blockIdx.x;
    const int n0 = g * C;
    const int n1 = (n0 + C < N) ? (n0 + C) : N;

    if (tid < BQ) thr_s[tid] = -FLT_MAX;
    __syncthreads();

    const float invct = 1.0f / ((float)(*ctp) + 1.0f);
    const float sq   = sinvq[qsel];
    const float qn2s = qn2[qsel];

    // ---- build q fragments once per block: B-operand layout ----
    // B[k][n]: lane l holds col=l&31, k = t*16 + (l>>5)*8 + j (j contiguous).
    u32x4 Bh[8], Bm[8], Bl[8];
    #pragma unroll
    for (int t = 0; t < 8; ++t) {
        float x[8];
        #pragma unroll
        for (int j = 0; j < 8; ++j)
            x[j] = qT[(t * 16 + hsel * 8 + j) * BQ + qsel];
        #pragma unroll
        for (int p = 0; p < 4; ++p) {
            unsigned h, m, l;
            split3(x[2 * p], x[2 * p + 1], h, m, l);
            Bh[t][p] = h; Bm[t][p] = m; Bl[t][p] = l;
        }
    }

    float top_s[TOPK]; int top_i[TOPK];
    #pragma unroll
    for (int j = 0; j < TOPK; ++j) { top_s[j] = -FLT_MAX; top_i[j] = 0; }
    float mind = FLT_MAX;

    const int rlast = n1 - 1;
    for (int rb = n0 + wave * 32; rb < n1; rb += 4 * 32) {
        // A row for this lane (clamped; invalid rows masked in score phase)
        const int arow = rb + qsel;
        const int arc  = (arow < rlast) ? arow : rlast;
        const float* rp = mem + (size_t)arc * DIM + hsel * 8;

        f32x16 acc = { 0.f, 0.f, 0.f, 0.f, 0.f, 0.f, 0.f, 0.f,
                       0.f, 0.f, 0.f, 0.f, 0.f, 0.f, 0.f, 0.f };
        float m2p = 0.0f;

        #pragma unroll
        for (int t = 0; t < 8; ++t) {
            const float4 xa = *(const float4*)(rp + t * 16);
            const float4 xb = *(const float4*)(rp + t * 16 + 4);
            const float xs[8] = { xa.x, xa.y, xa.z, xa.w, xb.x, xb.y, xb.z, xb.w };
            u32x4 Ah, Am, Al;
            #pragma unroll
            for (int p = 0; p < 4; ++p) {
                unsigned h, m, l;
                split3(xs[2 * p], xs[2 * p + 1], h, m, l);
                Ah[p] = h; Am[p] = m; Al[p] = l;
                m2p = fmaf(xs[2 * p], xs[2 * p], m2p);
                m2p = fmaf(xs[2 * p + 1], xs[2 * p + 1], m2p);
            }
            // accumulate small terms first
            acc = mfma32(Al, Bh[t], acc);
            acc = mfma32(Am, Bm[t], acc);
            acc = mfma32(Ah, Bl[t], acc);
            acc = mfma32(Am, Bh[t], acc);
            acc = mfma32(Ah, Bm[t], acc);
            acc = mfma32(Ah, Bh[t], acc);
        }

        // per-row constants (row = rb + qsel); halves hold complementary k-chunks
        const float m2full = m2p + __shfl_xor(m2p, 32);
        const int crow = rb + qsel;
        const int crc  = (crow < rlast) ? crow : rlast;
        const float impf = fmaf(0.5f, imp[crc], 0.5f);
        const float recn = ((float)tsp[crc] + 1.0f) * invct;
        const float invm = rsqrtf(m2full);
        cbuf[wave][qsel] = make_float4(0.7f * invm * impf,
                                       0.3f * recn * impf,
                                       m2full,
                                       (crow < n1) ? 1.0f : -1.0f);
        // block-shared threshold (stale-read is safe: monotone-valid bound)
        const float thrq = thr_s[qsel];

        // wave-private LDS; same-wave ds ordering, no barrier needed
        #pragma unroll
        for (int reg = 0; reg < 16; ++reg) {
            const int r = (reg & 3) + 8 * (reg >> 2) + 4 * hsel;
            const float4 cc = cbuf[wave][r];
            const float dot = acc[reg];
            const float score = fmaf(dot, cc.x * sq, cc.y);
            const float d2 = fmaf(-2.0f, dot, qn2s + cc.z);
            if (cc.w > 0.0f) {
                mind = fminf(mind, d2);
                if (score > fmaxf(top_s[TOPK - 1], thrq)) {
                    float cs = score; int ci = rb + r;
                    #pragma unroll
                    for (int p = 0; p < TOPK; ++p) {
                        const bool gt = cs > top_s[p];
                        const float tv = top_s[p]; const int tx = top_i[p];
                        top_s[p] = gt ? cs : tv;  top_i[p] = gt ? ci : tx;
                        cs = gt ? tv : cs;        ci = gt ? tx : ci;
                    }
                }
            }
        }
        // publish this stream's 16th-best as a block-wide discard bound.
        // Benign race: any written value is some stream's valid bound.
        if (top_s[TOPK - 1] > thrq) thr_s[qsel] = top_s[TOPK - 1];
    }

    // ---- block merge: dump lists to LDS, per-query 128 -> 16 extraction ----
    __syncthreads();
    #pragma unroll
    for (int j = 0; j < TOPK; ++j) {
        dsc[tid * TOPK + j] = top_s[j];
        dix[tid * TOPK + j] = top_i[j];
    }
    dmn[tid] = mind;
    __syncthreads();

    for (int qq = 0; qq < 8; ++qq) {
        const int q = wave * 8 + qq;
        // 8 lists of 16 -> 128 candidates; 2 per lane
        float sc2[2]; int ix2[2];
        #pragma unroll
        for (int s = 0; s < 2; ++s) {
            const int c = lane * 2 + s;
            const int L = (c >> 4) * 32 + q;
            const int slot = c & 15;
            sc2[s] = dsc[L * TOPK + slot];
            ix2[s] = dix[L * TOPK + slot];
        }
        float lm = (sc2[0] >= sc2[1]) ? sc2[0] : sc2[1];
        int   ls = (sc2[0] >= sc2[1]) ? 0 : 1;
        for (int r = 0; r < TOPK; ++r) {
            float v = lm; int we = lane;
            #pragma unroll
            for (int off = 32; off >= 1; off >>= 1) {
                const float ov = __shfl_xor(v, off);
                const int   oe = __shfl_xor(we, off);
                if (ov > v || (ov == v && oe < we)) { v = ov; we = oe; }
            }
            if (lane == we) {
                cand_sc[(g * 32 + q) * TOPK + r] = lm;
                cand_ix[(g * 32 + q) * TOPK + r] = ix2[ls];
                sc2[ls] = -FLT_MAX;
                lm = (sc2[0] >= sc2[1]) ? sc2[0] : sc2[1];
                ls = (sc2[0] >= sc2[1]) ? 0 : 1;
            }
        }
    }

    if (tid < 32) {
        float m = FLT_MAX;
        #pragma unroll
        for (int l = 0; l < 8; ++l) m = fminf(m, dmn[l * 32 + tid]);
        minD_ws[g * 32 + tid] = m;
    }
}

// ---------------- phase 2: global top-16/query + novelty ----------
__global__ void ph2_final(const float* __restrict__ cand_sc, const int* __restrict__ cand_ix,
                          const float* __restrict__ minD_ws, float* __restrict__ out, int G)
{
    __shared__ float ssc[NCAND];          // 48 KB
    __shared__ float shv[4];
    __shared__ int   she[4];
    __shared__ float smin[T2];

    const int q = blockIdx.x;
    const int tid = threadIdx.x;
    const int wave = tid >> 6;
    const int lane = tid & 63;

    for (int e = tid; e < NCAND; e += T2)
        ssc[e] = cand_sc[(e >> 4) * (32 * TOPK) + q * TOPK + (e & 15)];
    __syncthreads();

    // local argmax over this thread's 48 slots (e = s*256 + tid)
    float lm = ssc[tid]; int le = tid;
    for (int s = 1; s < NCAND / T2; ++s) {
        const int e = s * T2 + tid;
        const float v = ssc[e];
        if (v > lm) { lm = v; le = e; }
    }

    for (int r = 0; r < TOPK; ++r) {
        float v = lm; int e = le;
        #pragma unroll
        for (int off = 32; off >= 1; off >>= 1) {
            const float ov = __shfl_xor(v, off);
            const int   oe = __shfl_xor(e, off);
            if (ov > v || (ov == v && oe < e)) { v = ov; e = oe; }
        }
        if (lane == 0) { shv[wave] = v; she[wave] = e; }
        __syncthreads();
        float bv = shv[0]; int be = she[0];
        #pragma unroll
        for (int w2 = 1; w2 < 4; ++w2) {
            const float wv = shv[w2]; const int we2 = she[w2];
            if (wv > bv || (wv == bv && we2 < be)) { bv = wv; be = we2; }
        }
        if (le == be) {   // unique winner thread
            out[q * TOPK + r] = bv;
            const int gix = cand_ix[(be >> 4) * (32 * TOPK) + q * TOPK + (be & 15)];
            out[BQ * TOPK + q * TOPK + r] = (float)gix;
            ssc[le] = -FLT_MAX;
            lm = ssc[tid]; le = tid;
            for (int s = 1; s < NCAND / T2; ++s) {
                const int e2 = s * T2 + tid;
                const float v2 = ssc[e2];
                if (v2 > lm) { lm = v2; le = e2; }
            }
        }
        __syncthreads();
    }

    // novelty
    float m = FLT_MAX;
    for (int g2 = tid; g2 < G; g2 += T2) m = fminf(m, minD_ws[g2 * 32 + q]);
    smin[tid] = m;
    __syncthreads();
    for (int off = T2 / 2; off >= 1; off >>= 1) {
        if (tid < off) smin[tid] = fminf(smin[tid], smin[tid + off]);
        __syncthreads();
    }
    if (tid == 0) {
        const float md = sqrtf(fmaxf(smin[0], 0.0f));
        out[2 * BQ * TOPK + q] = fminf(1.0f, md * 0.1f);
    }
}

extern "C" void kernel_launch(void* const* d_in, const int* in_sizes, int n_in,
                              void* d_out, int out_size, void* d_ws, size_t ws_size,
                              hipStream_t stream) {
    const float* query      = (const float*)d_in[0];
    const float* memory     = (const float*)d_in[1];
    const float* importance = (const float*)d_in[2];
    const int*   timestamps = (const int*)d_in[3];
    const float* Wq         = (const float*)d_in[4];
    const float* bq         = (const float*)d_in[5];
    const int*   ctp        = (const int*)d_in[6];
    const int N = in_sizes[2];

    float* ws      = (float*)d_ws;
    float* qT      = ws;                       // 4096
    float* qn2     = ws + 4096;                // 32
    float* sinvq   = ws + 4128;                // 32
    float* cand_sc = ws + 4352;                // G1*32*16 = 393216
    int*   cand_ix = (int*)(ws + 4352 + G1 * 32 * TOPK);
    float* minD_ws = ws + 4352 + 2 * G1 * 32 * TOPK;  // G1*32

    const int C = (N + G1 - 1) / G1;           // rows per block

    ph0_qproj<<<BQ, DIM, 0, stream>>>(query, Wq, bq, qT, qn2, sinvq);
    ph1_scan<<<G1, T1, 0, stream>>>(memory, importance, timestamps, qT, sinvq, qn2,
                                    ctp, cand_sc, cand_ix, minD_ws, N, C);
    ph2_final<<<BQ, T2, 0, stream>>>(cand_sc, cand_ix, minD_ws, (float*)d_out, G1);
}

// Round 3
// 821.117 us; speedup vs baseline: 1.1347x; 1.0557x over previous
//
#include <hip/hip_runtime.h>
#include <float.h>

// Problem constants (B=32 queries, D=128, K=16).
#define BQ 32
#define DIM 128
#define TOPK 16
#define G1 512          // phase-1 blocks (exactly 2 per CU)
#define T1 256          // phase-1 threads (4 waves)
#define T2 256          // phase-2 threads
#define NCAND (G1*16)   // candidates per query entering phase 2 = 8192

typedef float f32x16 __attribute__((ext_vector_type(16)));
typedef __bf16 bf16x8 __attribute__((ext_vector_type(8)));
typedef unsigned int u32x4 __attribute__((ext_vector_type(4)));

// pack: low16 = bf16_rne(a), high16 = bf16_rne(b)
static __device__ __forceinline__ unsigned cvt_pk_bf16(float a, float b) {
    unsigned r;
    asm("v_cvt_pk_bf16_f32 %0, %1, %2" : "=v"(r) : "v"(a), "v"(b));
    return r;
}

// 3-level RNE bf16 split of a float pair. x = h + m + l + O(2^-27 |x|).
static __device__ __forceinline__ void split3(float f0, float f1,
                                              unsigned &h01, unsigned &m01, unsigned &l01) {
    h01 = cvt_pk_bf16(f0, f1);
    float r0 = f0 - __uint_as_float(h01 << 16);
    float r1 = f1 - __uint_as_float(h01 & 0xffff0000u);
    m01 = cvt_pk_bf16(r0, r1);
    float s0 = r0 - __uint_as_float(m01 << 16);
    float s1 = r1 - __uint_as_float(m01 & 0xffff0000u);
    l01 = cvt_pk_bf16(s0, s1);
}

static __device__ __forceinline__ f32x16 mfma32(u32x4 a, u32x4 b, f32x16 c) {
    return __builtin_amdgcn_mfma_f32_32x32x16_bf16(
        __builtin_bit_cast(bf16x8, a), __builtin_bit_cast(bf16x8, b), c, 0, 0, 0);
}

// issue 8 dwordx4 loads for half-tile (floats [h*64, h*64+64) of this lane's row)
#define LOADH(H, base) \
    _Pragma("unroll") \
    for (int j = 0; j < 4; ++j) { \
        H[2*j]   = *(const float4*)((base) + j*16); \
        H[2*j+1] = *(const float4*)((base) + j*16 + 4); \
    }

// 4 t-steps of split + 6-pass MFMA from half-buffer H (t = tb..tb+3)
#define COMPUTEH(H, tb) \
    _Pragma("unroll") \
    for (int tt = 0; tt < 4; ++tt) { \
        const int t = (tb) + tt; \
        const float4 xa = H[2*tt]; \
        const float4 xb = H[2*tt+1]; \
        const float xs[8] = { xa.x, xa.y, xa.z, xa.w, xb.x, xb.y, xb.z, xb.w }; \
        u32x4 Ah, Am, Al; \
        _Pragma("unroll") \
        for (int p = 0; p < 4; ++p) { \
            unsigned h, m, l; \
            split3(xs[2*p], xs[2*p+1], h, m, l); \
            Ah[p] = h; Am[p] = m; Al[p] = l; \
            m2p = fmaf(xs[2*p], xs[2*p], m2p); \
            m2p = fmaf(xs[2*p+1], xs[2*p+1], m2p); \
        } \
        acc = mfma32(Al, Bh[t], acc); \
        acc = mfma32(Am, Bm[t], acc); \
        acc = mfma32(Ah, Bl[t], acc); \
        acc = mfma32(Am, Bh[t], acc); \
        acc = mfma32(Ah, Bm[t], acc); \
        acc = mfma32(Ah, Bh[t], acc); \
    }

// ---------------- phase 0: q = query @ Wq^T + bq (stored transposed) + norms ----------
__global__ void ph0_qproj(const float* __restrict__ query, const float* __restrict__ Wq,
                          const float* __restrict__ bq,
                          float* __restrict__ qT, float* __restrict__ qn2,
                          float* __restrict__ sinvq)
{
    const int b = blockIdx.x;     // query row
    const int d = threadIdx.x;    // output dim
    float s = bq[d];
    #pragma unroll 8
    for (int kk = 0; kk < DIM; ++kk)
        s = fmaf(query[b * DIM + kk], Wq[d * DIM + kk], s);
    qT[d * BQ + b] = s;
    __shared__ float red[DIM];
    red[d] = s * s;
    __syncthreads();
    for (int off = DIM / 2; off >= 1; off >>= 1) {
        if (d < off) red[d] += red[d + off];
        __syncthreads();
    }
    if (d == 0) {
        qn2[b] = red[0];
        sinvq[b] = 1.0f / sqrtf(red[0]);
    }
}

// ---------------- phase 1: MFMA scores + per-block top-16/query + min-d2 ----------
// Per wave: 32-row x 32-query tile via v_mfma_f32_32x32x16_bf16, fp32 emulated by
// 3-way bf16 split (6 passes).  C-layout: col(query)=lane&31,
// row=(reg&3)+8*(reg>>2)+4*(lane>>5)  [m74/m101-verified].
// Memory pipeline: half-tile register double-buffer (H0/H1), loads issued ahead of
// compute with sched_barrier(0) pinning -> ~8KB in flight per wave.
__global__ __launch_bounds__(T1, 2) void ph1_scan(
    const float* __restrict__ mem, const float* __restrict__ imp,
    const int* __restrict__ tsp, const float* __restrict__ qT,
    const float* __restrict__ sinvq, const float* __restrict__ qn2,
    const int* __restrict__ ctp,
    float* __restrict__ cand_sc, int* __restrict__ cand_ix,
    float* __restrict__ minD_ws, int N, int C)
{
    __shared__ float dsc[T1 * TOPK];          // 16 KB
    __shared__ int   dix[T1 * TOPK];          // 16 KB
    __shared__ float dmn[T1];                 // 1 KB
    __shared__ float4 cbuf[4][BQ];            // 2 KB: per-wave row constants
    __shared__ float thr_s[BQ];               // block-shared per-query score bound

    const int tid  = threadIdx.x;
    const int wave = tid >> 6;
    const int lane = tid & 63;
    const int qsel = lane & 31;               // query for score phase; row for A/consts
    const int hsel = lane >> 5;
    const int g = blockIdx.x;
    const int n0 = g * C;
    const int n1 = (n0 + C < N) ? (n0 + C) : N;

    if (tid < BQ) thr_s[tid] = -FLT_MAX;
    __syncthreads();

    const float invct = 1.0f / ((float)(*ctp) + 1.0f);
    const float sq   = sinvq[qsel];
    const float qn2s = qn2[qsel];

    // ---- build q fragments once per block: B-operand layout ----
    // B[k][n]: lane l holds col=l&31, k = t*16 + (l>>5)*8 + j (j contiguous).
    u32x4 Bh[8], Bm[8], Bl[8];
    #pragma unroll
    for (int t = 0; t < 8; ++t) {
        float x[8];
        #pragma unroll
        for (int j = 0; j < 8; ++j)
            x[j] = qT[(t * 16 + hsel * 8 + j) * BQ + qsel];
        #pragma unroll
        for (int p = 0; p < 4; ++p) {
            unsigned h, m, l;
            split3(x[2 * p], x[2 * p + 1], h, m, l);
            Bh[t][p] = h; Bm[t][p] = m; Bl[t][p] = l;
        }
    }

    float top_s[TOPK]; int top_i[TOPK];
    #pragma unroll
    for (int j = 0; j < TOPK; ++j) { top_s[j] = -FLT_MAX; top_i[j] = 0; }
    float mind = FLT_MAX;

    const int rlast = n1 - 1;

    float4 H0[8], H1[8];
    int rb = n0 + wave * 32;
    {   // prologue: first half-tile of first tile
        const int arow0 = rb + qsel;
        const int arc0  = (arow0 < rlast) ? arow0 : rlast;
        const float* rp0 = mem + (size_t)arc0 * DIM + hsel * 8;
        LOADH(H0, rp0);
    }
    const int arowp = rb + qsel;
    const float* rp = mem + (size_t)((arowp < rlast) ? arowp : rlast) * DIM + hsel * 8;

    for (; rb < n1; rb += 128) {
        // issue second half-tile + per-row scalar loads up front
        LOADH(H1, rp + 64);
        const int crow = rb + qsel;
        const int crc  = (crow < rlast) ? crow : rlast;
        const float iv = imp[crc];
        const float tv = (float)tsp[crc];
        const float thrq = thr_s[qsel];
        __builtin_amdgcn_sched_barrier(0);

        f32x16 acc = { 0.f, 0.f, 0.f, 0.f, 0.f, 0.f, 0.f, 0.f,
                       0.f, 0.f, 0.f, 0.f, 0.f, 0.f, 0.f, 0.f };
        float m2p = 0.0f;

        COMPUTEH(H0, 0);

        // issue next tile's first half-tile while computing H1
        const int rbn = rb + 128;
        const int arown = rbn + qsel;
        const int arcn  = (arown < rlast) ? arown : rlast;
        const float* rpn = (rbn < n1) ? (mem + (size_t)arcn * DIM + hsel * 8) : rp;
        LOADH(H0, rpn);
        __builtin_amdgcn_sched_barrier(0);

        COMPUTEH(H1, 4);

        // per-row constants (row = rb + qsel); halves hold complementary k-chunks
        const float m2full = m2p + __shfl_xor(m2p, 32);
        const float impf = fmaf(0.5f, iv, 0.5f);
        const float recn = (tv + 1.0f) * invct;
        const float invm = rsqrtf(m2full);
        cbuf[wave][qsel] = make_float4(0.7f * invm * impf,
                                       0.3f * recn * impf,
                                       m2full,
                                       (crow < n1) ? 1.0f : -1.0f);

        // wave-private LDS; same-wave ds ordering, no barrier needed
        #pragma unroll
        for (int reg = 0; reg < 16; ++reg) {
            const int r = (reg & 3) + 8 * (reg >> 2) + 4 * hsel;
            const float4 cc = cbuf[wave][r];
            const float dot = acc[reg];
            const float score = fmaf(dot, cc.x * sq, cc.y);
            const float d2 = fmaf(-2.0f, dot, qn2s + cc.z);
            if (cc.w > 0.0f) {
                mind = fminf(mind, d2);
                if (score > fmaxf(top_s[TOPK - 1], thrq)) {
                    float cs = score; int ci = rb + r;
                    #pragma unroll
                    for (int p = 0; p < TOPK; ++p) {
                        const bool gt = cs > top_s[p];
                        const float tv2 = top_s[p]; const int tx = top_i[p];
                        top_s[p] = gt ? cs : tv2;  top_i[p] = gt ? ci : tx;
                        cs = gt ? tv2 : cs;        ci = gt ? tx : ci;
                    }
                }
            }
        }
        // publish this stream's 16th-best as a block-wide discard bound.
        // Benign race: any written value is some stream's valid bound.
        if (top_s[TOPK - 1] > thrq) thr_s[qsel] = top_s[TOPK - 1];

        rp = rpn;
    }

    // ---- block merge: dump lists to LDS, per-query 128 -> 16 extraction ----
    __syncthreads();
    #pragma unroll
    for (int j = 0; j < TOPK; ++j) {
        dsc[tid * TOPK + j] = top_s[j];
        dix[tid * TOPK + j] = top_i[j];
    }
    dmn[tid] = mind;
    __syncthreads();

    for (int qq = 0; qq < 8; ++qq) {
        const int q = wave * 8 + qq;
        // 8 lists of 16 -> 128 candidates; 2 per lane
        float sc2[2]; int ix2[2];
        #pragma unroll
        for (int s = 0; s < 2; ++s) {
            const int c = lane * 2 + s;
            const int L = (c >> 4) * 32 + q;
            const int slot = c & 15;
            sc2[s] = dsc[L * TOPK + slot];
            ix2[s] = dix[L * TOPK + slot];
        }
        float lm = (sc2[0] >= sc2[1]) ? sc2[0] : sc2[1];
        int   ls = (sc2[0] >= sc2[1]) ? 0 : 1;
        for (int r = 0; r < TOPK; ++r) {
            float v = lm; int we = lane;
            #pragma unroll
            for (int off = 32; off >= 1; off >>= 1) {
                const float ov = __shfl_xor(v, off);
                const int   oe = __shfl_xor(we, off);
                if (ov > v || (ov == v && oe < we)) { v = ov; we = oe; }
            }
            if (lane == we) {
                cand_sc[(g * 32 + q) * TOPK + r] = lm;
                cand_ix[(g * 32 + q) * TOPK + r] = ix2[ls];
                sc2[ls] = -FLT_MAX;
                lm = (sc2[0] >= sc2[1]) ? sc2[0] : sc2[1];
                ls = (sc2[0] >= sc2[1]) ? 0 : 1;
            }
        }
    }

    if (tid < 32) {
        float m = FLT_MAX;
        #pragma unroll
        for (int l = 0; l < 8; ++l) m = fminf(m, dmn[l * 32 + tid]);
        minD_ws[g * 32 + tid] = m;
    }
}

// ---------------- phase 2: global top-16/query + novelty ----------
__global__ void ph2_final(const float* __restrict__ cand_sc, const int* __restrict__ cand_ix,
                          const float* __restrict__ minD_ws, float* __restrict__ out, int G)
{
    __shared__ float ssc[NCAND];          // 32 KB
    __shared__ float shv[4];
    __shared__ int   she[4];
    __shared__ float smin[T2];

    const int q = blockIdx.x;
    const int tid = threadIdx.x;
    const int wave = tid >> 6;
    const int lane = tid & 63;

    for (int e = tid; e < NCAND; e += T2)
        ssc[e] = cand_sc[(e >> 4) * (32 * TOPK) + q * TOPK + (e & 15)];
    __syncthreads();

    // local argmax over this thread's 32 slots (e = s*256 + tid)
    float lm = ssc[tid]; int le = tid;
    for (int s = 1; s < NCAND / T2; ++s) {
        const int e = s * T2 + tid;
        const float v = ssc[e];
        if (v > lm) { lm = v; le = e; }
    }

    for (int r = 0; r < TOPK; ++r) {
        float v = lm; int e = le;
        #pragma unroll
        for (int off = 32; off >= 1; off >>= 1) {
            const float ov = __shfl_xor(v, off);
            const int   oe = __shfl_xor(e, off);
            if (ov > v || (ov == v && oe < e)) { v = ov; e = oe; }
        }
        if (lane == 0) { shv[wave] = v; she[wave] = e; }
        __syncthreads();
        float bv = shv[0]; int be = she[0];
        #pragma unroll
        for (int w2 = 1; w2 < 4; ++w2) {
            const float wv = shv[w2]; const int we2 = she[w2];
            if (wv > bv || (wv == bv && we2 < be)) { bv = wv; be = we2; }
        }
        if (le == be) {   // unique winner thread
            out[q * TOPK + r] = bv;
            const int gix = cand_ix[(be >> 4) * (32 * TOPK) + q * TOPK + (be & 15)];
            out[BQ * TOPK + q * TOPK + r] = (float)gix;
            ssc[le] = -FLT_MAX;
            lm = ssc[tid]; le = tid;
            for (int s = 1; s < NCAND / T2; ++s) {
                const int e2 = s * T2 + tid;
                const float v2 = ssc[e2];
                if (v2 > lm) { lm = v2; le = e2; }
            }
        }
        __syncthreads();
    }

    // novelty
    float m = FLT_MAX;
    for (int g2 = tid; g2 < G; g2 += T2) m = fminf(m, minD_ws[g2 * 32 + q]);
    smin[tid] = m;
    __syncthreads();
    for (int off = T2 / 2; off >= 1; off >>= 1) {
        if (tid < off) smin[tid] = fminf(smin[tid], smin[tid + off]);
        __syncthreads();
    }
    if (tid == 0) {
        const float md = sqrtf(fmaxf(smin[0], 0.0f));
        out[2 * BQ * TOPK + q] = fminf(1.0f, md * 0.1f);
    }
}

extern "C" void kernel_launch(void* const* d_in, const int* in_sizes, int n_in,
                              void* d_out, int out_size, void* d_ws, size_t ws_size,
                              hipStream_t stream) {
    const float* query      = (const float*)d_in[0];
    const float* memory     = (const float*)d_in[1];
    const float* importance = (const float*)d_in[2];
    const int*   timestamps = (const int*)d_in[3];
    const float* Wq         = (const float*)d_in[4];
    const float* bq         = (const float*)d_in[5];
    const int*   ctp        = (const int*)d_in[6];
    const int N = in_sizes[2];

    float* ws      = (float*)d_ws;
    float* qT      = ws;                       // 4096
    float* qn2     = ws + 4096;                // 32
    float* sinvq   = ws + 4128;                // 32
    float* cand_sc = ws + 4352;                // G1*32*16 = 262144
    int*   cand_ix = (int*)(ws + 4352 + G1 * 32 * TOPK);
    float* minD_ws = ws + 4352 + 2 * G1 * 32 * TOPK;  // G1*32

    const int C = (N + G1 - 1) / G1;           // rows per block

    ph0_qproj<<<BQ, DIM, 0, stream>>>(query, Wq, bq, qT, qn2, sinvq);
    ph1_scan<<<G1, T1, 0, stream>>>(memory, importance, timestamps, qT, sinvq, qn2,
                                    ctp, cand_sc, cand_ix, minD_ws, N, C);
    ph2_final<<<BQ, T2, 0, stream>>>(cand_sc, cand_ix, minD_ws, (float*)d_out, G1);
}